// Round 1
// baseline (88.489 us; speedup 1.0000x reference)
//
#include <hip/hip_runtime.h>
#include <hip/hip_bf16.h>

// GAT layer, N=4096, C_IN=C_OUT=256, HEADS=4, C_HEAD=64.
// Pipeline:
//  K1: h = X @ W^T + b          (bf16 MFMA, fp32 out, 4 MB ws)
//  K2a: e_src/e_dst (x log2e)   (fp32, 64 KB each)
//  K2b: hB = h in MFMA-B-fragment order, bf16 (2 MB)
//  K3: flash-style masked softmax + P@H, j-split x2 across blocks
//  K4: merge the two j-split partials
// Workspace requirement: ~15 MB.

#define NN 4096
#define LOG2E 1.4426950408889634f
#define FILL2 (-9.0e15f * 1.4426950408889634f)

typedef float f32x4 __attribute__((ext_vector_type(4)));
typedef int i32x4 __attribute__((ext_vector_type(4)));
typedef unsigned short u16x8 __attribute__((ext_vector_type(8)));
typedef __bf16 bf16x8 __attribute__((ext_vector_type(8)));

__device__ __forceinline__ unsigned short f2bf_rne(float f) {
    unsigned int u = __builtin_bit_cast(unsigned int, f);
    u += 0x7fffu + ((u >> 16) & 1u);
    return (unsigned short)(u >> 16);
}

__device__ __forceinline__ bf16x8 ld_cvt8(const float* __restrict__ p) {
    f32x4 x = *(const f32x4*)p;
    f32x4 y = *(const f32x4*)(p + 4);
    u16x8 u;
    u[0] = f2bf_rne(x[0]); u[1] = f2bf_rne(x[1]); u[2] = f2bf_rne(x[2]); u[3] = f2bf_rne(x[3]);
    u[4] = f2bf_rne(y[0]); u[5] = f2bf_rne(y[1]); u[6] = f2bf_rne(y[2]); u[7] = f2bf_rne(y[3]);
    return __builtin_bit_cast(bf16x8, u);
}

// ---------------- K1: h = X @ W^T + bias (fp32 out) ----------------
// 128 blocks x 256 thr. Block covers 32 rows; wave w covers cols [64w,64w+64).
__global__ __launch_bounds__(256) void k1_gemm(const float* __restrict__ X,
                                               const float* __restrict__ W,
                                               const float* __restrict__ bias,
                                               float* __restrict__ h) {
    const int lane = threadIdx.x & 63;
    const int wv   = threadIdx.x >> 6;      // 0..3 column group
    const int row  = lane & 15;
    const int kg   = lane >> 4;
    const int rowbase = blockIdx.x * 32;
    const int colbase = wv * 64;

    f32x4 acc0[4], acc1[4];
#pragma unroll
    for (int n = 0; n < 4; ++n) { acc0[n] = (f32x4)0.f; acc1[n] = (f32x4)0.f; }

#pragma unroll
    for (int kk = 0; kk < 8; ++kk) {
        const int kb = kk * 32 + kg * 8;
        bf16x8 a0 = ld_cvt8(X + (rowbase + row) * 256 + kb);
        bf16x8 a1 = ld_cvt8(X + (rowbase + 16 + row) * 256 + kb);
#pragma unroll
        for (int n = 0; n < 4; ++n) {
            bf16x8 bb = ld_cvt8(W + (colbase + n * 16 + row) * 256 + kb);
            acc0[n] = __builtin_amdgcn_mfma_f32_16x16x32_bf16(a0, bb, acc0[n], 0, 0, 0);
            acc1[n] = __builtin_amdgcn_mfma_f32_16x16x32_bf16(a1, bb, acc1[n], 0, 0, 0);
        }
    }
#pragma unroll
    for (int n = 0; n < 4; ++n) {
        const int col = colbase + n * 16 + row;
        const float bv = bias[col];
#pragma unroll
        for (int r = 0; r < 4; ++r) {
            h[(rowbase + 4 * kg + r) * 256 + col]      = acc0[n][r] + bv;
            h[(rowbase + 16 + 4 * kg + r) * 256 + col] = acc1[n][r] + bv;
        }
    }
}

// ---------------- K2a: e_src/e_dst (scaled by log2e) ----------------
// 1024 blocks x 256 thr; one wave per node row.
__global__ __launch_bounds__(256) void k2_edges(const float* __restrict__ h,
                                                const float* __restrict__ a,
                                                float* __restrict__ esrc,
                                                float* __restrict__ edst) {
    const int lane = threadIdx.x & 63;
    const int r = blockIdx.x * 4 + (threadIdx.x >> 6);
    const int head = lane >> 4;
    const int off = (lane & 15) * 4;
    f32x4 hv = *(const f32x4*)(h + r * 256 + lane * 4);
    f32x4 as = *(const f32x4*)(a + head * 128 + off);
    f32x4 ad = *(const f32x4*)(a + head * 128 + 64 + off);
    float es = hv[0] * as[0] + hv[1] * as[1] + hv[2] * as[2] + hv[3] * as[3];
    float ed = hv[0] * ad[0] + hv[1] * ad[1] + hv[2] * ad[2] + hv[3] * ad[3];
#pragma unroll
    for (int d = 1; d < 16; d <<= 1) {
        es += __shfl_xor(es, d);
        ed += __shfl_xor(ed, d);
    }
    if ((lane & 15) == 0) {
        esrc[head * NN + r] = es * LOG2E;
        edst[head * NN + r] = ed * LOG2E;
    }
}

// ---------------- K2b: build hB in B-fragment order (bf16) ----------------
// hB[(((h*128 + t)*4 + n)*64 + lane)*8 + e] = h[t*32 + 8*(lane>>4)+e][h*64 + 16n + (lane&15)]
__global__ __launch_bounds__(256) void k2_swizzle(const float* __restrict__ h,
                                                  unsigned short* __restrict__ hB) {
    const int gid = blockIdx.x * 256 + threadIdx.x;  // 131072 total
    const int lane = gid & 63;
    const int n  = (gid >> 6) & 3;
    const int t  = (gid >> 8) & 127;
    const int hh = (gid >> 15) & 3;
    const int jb = t * 32 + (lane >> 4) * 8;
    const int c  = hh * 64 + n * 16 + (lane & 15);
    u16x8 u;
#pragma unroll
    for (int e = 0; e < 8; ++e) u[e] = f2bf_rne(h[(jb + e) * 256 + c]);
    *(u16x8*)(hB + ((((hh * 128 + t) * 4 + n) * 64 + lane) * 8)) = u;
}

// ---------------- K3: flash masked-softmax + P@H ----------------
// grid 256: q = bx&1 (j-half), ib = bx>>1. 8 waves = 4 heads x 2 rowgroups (16 rows each).
#define K3_LOAD(S, T)                                        \
    A0##S = *(const i32x4*)(aRow + (T) * 32);                \
    A1##S = *(const i32x4*)(aRow + (T) * 32 + 4);            \
    E0##S = *(const f32x4*)(eD + (T) * 32);                  \
    E1##S = *(const f32x4*)(eD + (T) * 32 + 4);              \
    B0##S = *(const u16x8*)(hBp + (T) * 2048);               \
    B1##S = *(const u16x8*)(hBp + (T) * 2048 + 512);         \
    B2##S = *(const u16x8*)(hBp + (T) * 2048 + 1024);        \
    B3##S = *(const u16x8*)(hBp + (T) * 2048 + 1536);

#define K3_COMPUTE(S) {                                                          \
    float s0 = es + E0##S[0], s1 = es + E0##S[1], s2 = es + E0##S[2], s3 = es + E0##S[3]; \
    float s4 = es + E1##S[0], s5 = es + E1##S[1], s6 = es + E1##S[2], s7 = es + E1##S[3]; \
    s0 = fmaxf(s0, 0.2f * s0); s1 = fmaxf(s1, 0.2f * s1);                        \
    s2 = fmaxf(s2, 0.2f * s2); s3 = fmaxf(s3, 0.2f * s3);                        \
    s4 = fmaxf(s4, 0.2f * s4); s5 = fmaxf(s5, 0.2f * s5);                        \
    s6 = fmaxf(s6, 0.2f * s6); s7 = fmaxf(s7, 0.2f * s7);                        \
    s0 = (A0##S[0] != 0) ? s0 : FILL2; s1 = (A0##S[1] != 0) ? s1 : FILL2;        \
    s2 = (A0##S[2] != 0) ? s2 : FILL2; s3 = (A0##S[3] != 0) ? s3 : FILL2;        \
    s4 = (A1##S[0] != 0) ? s4 : FILL2; s5 = (A1##S[1] != 0) ? s5 : FILL2;        \
    s6 = (A1##S[2] != 0) ? s6 : FILL2; s7 = (A1##S[3] != 0) ? s7 : FILL2;        \
    float tm = fmaxf(fmaxf(fmaxf(s0, s1), fmaxf(s2, s3)),                        \
                     fmaxf(fmaxf(s4, s5), fmaxf(s6, s7)));                       \
    tm = fmaxf(tm, __shfl_xor(tm, 16));                                          \
    tm = fmaxf(tm, __shfl_xor(tm, 32));                                          \
    float mn = fmaxf(m, tm);                                                     \
    if (__any(tm > m)) {                                                         \
        float al = __builtin_exp2f(m - mn);                                      \
        ls *= al;                                                                \
        f32x4 av;                                                                \
        av[0] = __shfl(al, kg4);     av[1] = __shfl(al, kg4 + 1);                \
        av[2] = __shfl(al, kg4 + 2); av[3] = __shfl(al, kg4 + 3);                \
        acc0 *= av; acc1 *= av; acc2 *= av; acc3 *= av;                          \
        m = mn;                                                                  \
    }                                                                            \
    float p0 = __builtin_exp2f(s0 - m), p1 = __builtin_exp2f(s1 - m);            \
    float p2 = __builtin_exp2f(s2 - m), p3 = __builtin_exp2f(s3 - m);            \
    float p4 = __builtin_exp2f(s4 - m), p5 = __builtin_exp2f(s5 - m);            \
    float p6 = __builtin_exp2f(s6 - m), p7 = __builtin_exp2f(s7 - m);            \
    ls += ((p0 + p1) + (p2 + p3)) + ((p4 + p5) + (p6 + p7));                     \
    u16x8 pu;                                                                    \
    pu[0] = (unsigned short)(__builtin_bit_cast(unsigned int, p0) >> 16);        \
    pu[1] = (unsigned short)(__builtin_bit_cast(unsigned int, p1) >> 16);        \
    pu[2] = (unsigned short)(__builtin_bit_cast(unsigned int, p2) >> 16);        \
    pu[3] = (unsigned short)(__builtin_bit_cast(unsigned int, p3) >> 16);        \
    pu[4] = (unsigned short)(__builtin_bit_cast(unsigned int, p4) >> 16);        \
    pu[5] = (unsigned short)(__builtin_bit_cast(unsigned int, p5) >> 16);        \
    pu[6] = (unsigned short)(__builtin_bit_cast(unsigned int, p6) >> 16);        \
    pu[7] = (unsigned short)(__builtin_bit_cast(unsigned int, p7) >> 16);        \
    bf16x8 af = __builtin_bit_cast(bf16x8, pu);                                  \
    acc0 = __builtin_amdgcn_mfma_f32_16x16x32_bf16(af, __builtin_bit_cast(bf16x8, B0##S), acc0, 0, 0, 0); \
    acc1 = __builtin_amdgcn_mfma_f32_16x16x32_bf16(af, __builtin_bit_cast(bf16x8, B1##S), acc1, 0, 0, 0); \
    acc2 = __builtin_amdgcn_mfma_f32_16x16x32_bf16(af, __builtin_bit_cast(bf16x8, B2##S), acc2, 0, 0, 0); \
    acc3 = __builtin_amdgcn_mfma_f32_16x16x32_bf16(af, __builtin_bit_cast(bf16x8, B3##S), acc3, 0, 0, 0); \
}

__global__ __launch_bounds__(512) void k3_flash(const int* __restrict__ adj,
                                                const unsigned short* __restrict__ hB,
                                                const float* __restrict__ esrc,
                                                const float* __restrict__ edst,
                                                float* __restrict__ pacc,
                                                float* __restrict__ pm,
                                                float* __restrict__ pl) {
    const int lane = threadIdx.x & 63;
    const int w  = threadIdx.x >> 6;  // 0..7
    const int hh = w & 3;             // head
    const int rg = w >> 2;            // row group
    const int q  = blockIdx.x & 1;    // j-half
    const int ib = blockIdx.x >> 1;   // 0..127
    const int i0 = ib * 32 + rg * 16;
    const int row = lane & 15;
    const int kg  = lane >> 4;
    const int kg4 = kg * 4;

    const float es = esrc[hh * NN + i0 + row];
    const int* aRow = adj + (i0 + row) * NN + q * 2048 + kg * 8;
    const float* eD = edst + hh * NN + q * 2048 + kg * 8;
    const unsigned short* hBp = hB + ((hh * 128 + q * 64) * 4 * 64 + lane) * 8;

    f32x4 acc0 = (f32x4)0.f, acc1 = (f32x4)0.f, acc2 = (f32x4)0.f, acc3 = (f32x4)0.f;
    float m = -INFINITY, ls = 0.f;

    i32x4 A0a, A1a, A0b, A1b;
    f32x4 E0a, E1a, E0b, E1b;
    u16x8 B0a, B1a, B2a, B3a, B0b, B1b, B2b, B3b;

    K3_LOAD(a, 0)
    for (int t = 0; t < 64; t += 2) {
        K3_LOAD(b, t + 1)
        K3_COMPUTE(a)
        if (t + 2 < 64) { K3_LOAD(a, t + 2) }
        K3_COMPUTE(b)
    }

    // finalize row sums (spread across the 4 k-groups)
    ls += __shfl_xor(ls, 16);
    ls += __shfl_xor(ls, 32);

#pragma unroll
    for (int r = 0; r < 4; ++r) {
        float* prow = pacc + q * (NN * 256) + (i0 + 4 * kg + r) * 256 + hh * 64 + row;
        prow[0]  = acc0[r];
        prow[16] = acc1[r];
        prow[32] = acc2[r];
        prow[48] = acc3[r];
    }
    if (lane < 16) {
        pm[(q * 4 + hh) * NN + i0 + lane] = m;
        pl[(q * 4 + hh) * NN + i0 + lane] = ls;
    }
}

// ---------------- K4: merge j-split partials ----------------
__global__ __launch_bounds__(256) void k4_merge(const float* __restrict__ pacc,
                                                const float* __restrict__ pm,
                                                const float* __restrict__ pl,
                                                float* __restrict__ out) {
    const int gid = blockIdx.x * 256 + threadIdx.x;  // 262144
    const int i  = gid >> 6;
    const int c4 = (gid & 63) * 4;
    const int hh = c4 >> 6;
    f32x4 A0 = *(const f32x4*)(pacc + i * 256 + c4);
    f32x4 A1 = *(const f32x4*)(pacc + NN * 256 + i * 256 + c4);
    float m0 = pm[hh * NN + i], m1 = pm[(4 + hh) * NN + i];
    float l0 = pl[hh * NN + i], l1 = pl[(4 + hh) * NN + i];
    float M = fmaxf(m0, m1);
    float a0 = __builtin_exp2f(m0 - M), a1 = __builtin_exp2f(m1 - M);
    float inv = 1.f / (l0 * a0 + l1 * a1);
    f32x4 o;
    o[0] = (A0[0] * a0 + A1[0] * a1) * inv;
    o[1] = (A0[1] * a0 + A1[1] * a1) * inv;
    o[2] = (A0[2] * a0 + A1[2] * a1) * inv;
    o[3] = (A0[3] * a0 + A1[3] * a1) * inv;
    *(f32x4*)(out + i * 256 + c4) = o;
}

extern "C" void kernel_launch(void* const* d_in, const int* in_sizes, int n_in,
                              void* d_out, int out_size, void* d_ws, size_t ws_size,
                              hipStream_t stream) {
    const float* X    = (const float*)d_in[0];
    const int*   adj  = (const int*)d_in[1];
    const float* W    = (const float*)d_in[2];
    const float* bias = (const float*)d_in[3];
    const float* a    = (const float*)d_in[4];
    float* out = (float*)d_out;

    char* ws = (char*)d_ws;
    float*          h    = (float*)(ws);                                  // 4 MB
    unsigned short* hB   = (unsigned short*)(ws + (4 << 20));             // 2 MB
    float*          esrc = (float*)(ws + (6 << 20));                      // 64 KB
    float*          edst = (float*)(ws + (6 << 20) + (64 << 10));         // 64 KB
    float*          pacc = (float*)(ws + (6 << 20) + (128 << 10));        // 8 MB
    float*          pm   = (float*)(ws + (6 << 20) + (128 << 10) + (8 << 20)); // 128 KB
    float*          pl   = pm + 2 * 4 * NN;                               // 128 KB

    k1_gemm<<<128, 256, 0, stream>>>(X, W, bias, h);
    k2_edges<<<1024, 256, 0, stream>>>(h, a, esrc, edst);
    k2_swizzle<<<512, 256, 0, stream>>>(h, hB);
    k3_flash<<<256, 512, 0, stream>>>(adj, hB, esrc, edst, pacc, pm, pl);
    k4_merge<<<1024, 256, 0, stream>>>(pacc, pm, pl, out);
}

// Round 2
// 74.225 us; speedup vs baseline: 1.1922x; 1.1922x over previous
//
#include <hip/hip_runtime.h>
#include <hip/hip_bf16.h>

// GAT layer, N=4096, C_IN=C_OUT=256, HEADS=4, C_HEAD=64.
// Pipeline:
//  K1: h = X @ W^T + b          (bf16 MFMA, fp32 out, 4 MB ws)
//  K2a: e_src/e_dst (x log2e)   (fp32, 16 KB each)
//  K2b: hB = h in MFMA-B-fragment order, bf16 (2 MB)
//  K3: masked softmax (fixed m=0, no online max) + P@H; 4 j-splits merged
//      through LDS inside the block; writes final out. No merge kernel.
// Workspace: ~6.2 MB.

#define NN 4096
#define LOG2E 1.4426950408889634f
#define NEGBIG -1.0e9f

typedef float f32x4 __attribute__((ext_vector_type(4)));
typedef int i32x4 __attribute__((ext_vector_type(4)));
typedef unsigned short u16x8 __attribute__((ext_vector_type(8)));
typedef __bf16 bf16x8 __attribute__((ext_vector_type(8)));

__device__ __forceinline__ unsigned short f2bf_rne(float f) {
    unsigned int u = __builtin_bit_cast(unsigned int, f);
    u += 0x7fffu + ((u >> 16) & 1u);
    return (unsigned short)(u >> 16);
}

__device__ __forceinline__ bf16x8 ld_cvt8(const float* __restrict__ p) {
    f32x4 x = *(const f32x4*)p;
    f32x4 y = *(const f32x4*)(p + 4);
    u16x8 u;
    u[0] = f2bf_rne(x[0]); u[1] = f2bf_rne(x[1]); u[2] = f2bf_rne(x[2]); u[3] = f2bf_rne(x[3]);
    u[4] = f2bf_rne(y[0]); u[5] = f2bf_rne(y[1]); u[6] = f2bf_rne(y[2]); u[7] = f2bf_rne(y[3]);
    return __builtin_bit_cast(bf16x8, u);
}

// ---------------- K1: h = X @ W^T + bias (fp32 out) ----------------
// 256 blocks x 256 thr. Block covers 16 rows; wave w covers cols [64w,64w+64).
__global__ __launch_bounds__(256) void k1_gemm(const float* __restrict__ X,
                                               const float* __restrict__ W,
                                               const float* __restrict__ bias,
                                               float* __restrict__ h) {
    const int lane = threadIdx.x & 63;
    const int wv   = threadIdx.x >> 6;      // 0..3 column group
    const int row  = lane & 15;
    const int kg   = lane >> 4;
    const int rowbase = blockIdx.x * 16;
    const int colbase = wv * 64;

    f32x4 acc0[4];
#pragma unroll
    for (int n = 0; n < 4; ++n) acc0[n] = (f32x4)0.f;

#pragma unroll
    for (int kk = 0; kk < 8; ++kk) {
        const int kb = kk * 32 + kg * 8;
        bf16x8 a0 = ld_cvt8(X + (rowbase + row) * 256 + kb);
#pragma unroll
        for (int n = 0; n < 4; ++n) {
            bf16x8 bb = ld_cvt8(W + (colbase + n * 16 + row) * 256 + kb);
            acc0[n] = __builtin_amdgcn_mfma_f32_16x16x32_bf16(a0, bb, acc0[n], 0, 0, 0);
        }
    }
#pragma unroll
    for (int n = 0; n < 4; ++n) {
        const int col = colbase + n * 16 + row;
        const float bv = bias[col];
#pragma unroll
        for (int r = 0; r < 4; ++r)
            h[(rowbase + 4 * kg + r) * 256 + col] = acc0[n][r] + bv;
    }
}

// ---------------- K2a: e_src/e_dst (scaled by log2e) ----------------
// 1024 blocks x 256 thr; one wave per node row.
__global__ __launch_bounds__(256) void k2_edges(const float* __restrict__ h,
                                                const float* __restrict__ a,
                                                float* __restrict__ esrc,
                                                float* __restrict__ edst) {
    const int lane = threadIdx.x & 63;
    const int r = blockIdx.x * 4 + (threadIdx.x >> 6);
    const int head = lane >> 4;
    const int off = (lane & 15) * 4;
    f32x4 hv = *(const f32x4*)(h + r * 256 + lane * 4);
    f32x4 as = *(const f32x4*)(a + head * 128 + off);
    f32x4 ad = *(const f32x4*)(a + head * 128 + 64 + off);
    float es = hv[0] * as[0] + hv[1] * as[1] + hv[2] * as[2] + hv[3] * as[3];
    float ed = hv[0] * ad[0] + hv[1] * ad[1] + hv[2] * ad[2] + hv[3] * ad[3];
#pragma unroll
    for (int d = 1; d < 16; d <<= 1) {
        es += __shfl_xor(es, d);
        ed += __shfl_xor(ed, d);
    }
    if ((lane & 15) == 0) {
        esrc[head * NN + r] = es * LOG2E;
        edst[head * NN + r] = ed * LOG2E;
    }
}

// ---------------- K2b: build hB in B-fragment order (bf16) ----------------
// hB[(((h*128 + t)*4 + n)*64 + lane)*8 + e] = h[t*32 + 8*(lane>>4)+e][h*64 + 16n + (lane&15)]
__global__ __launch_bounds__(256) void k2_swizzle(const float* __restrict__ h,
                                                  unsigned short* __restrict__ hB) {
    const int gid = blockIdx.x * 256 + threadIdx.x;  // 131072 total
    const int lane = gid & 63;
    const int n  = (gid >> 6) & 3;
    const int t  = (gid >> 8) & 127;
    const int hh = (gid >> 15) & 3;
    const int jb = t * 32 + (lane >> 4) * 8;
    const int c  = hh * 64 + n * 16 + (lane & 15);
    u16x8 u;
#pragma unroll
    for (int e = 0; e < 8; ++e) u[e] = f2bf_rne(h[(jb + e) * 256 + c]);
    *(u16x8*)(hB + ((((hh * 128 + t) * 4 + n) * 64 + lane) * 8)) = u;
}

// ---------------- K3: masked softmax (m=0) + P@H, LDS-merged j-splits ----------------
// grid 512: ib = bx>>1 (16 rows), hb = bx&1 (head pair).
// 8 waves = 4 j-splits (q = w>>1) x 2 heads (hd = w&1). Each wave: 16 rows x 1024 j.
#define K3_LOAD(S, T)                                        \
    A0##S = *(const i32x4*)(aRow + (T) * 32);                \
    A1##S = *(const i32x4*)(aRow + (T) * 32 + 4);            \
    E0##S = *(const f32x4*)(eD + (T) * 32);                  \
    E1##S = *(const f32x4*)(eD + (T) * 32 + 4);              \
    B0##S = *(const u16x8*)(hBp + (T) * 2048);               \
    B1##S = *(const u16x8*)(hBp + (T) * 2048 + 512);         \
    B2##S = *(const u16x8*)(hBp + (T) * 2048 + 1024);        \
    B3##S = *(const u16x8*)(hBp + (T) * 2048 + 1536);

#define K3_COMPUTE(S) {                                                          \
    float s0 = es + E0##S[0], s1 = es + E0##S[1], s2 = es + E0##S[2], s3 = es + E0##S[3]; \
    float s4 = es + E1##S[0], s5 = es + E1##S[1], s6 = es + E1##S[2], s7 = es + E1##S[3]; \
    s0 = fmaxf(s0, 0.2f * s0); s1 = fmaxf(s1, 0.2f * s1);                        \
    s2 = fmaxf(s2, 0.2f * s2); s3 = fmaxf(s3, 0.2f * s3);                        \
    s4 = fmaxf(s4, 0.2f * s4); s5 = fmaxf(s5, 0.2f * s5);                        \
    s6 = fmaxf(s6, 0.2f * s6); s7 = fmaxf(s7, 0.2f * s7);                        \
    s0 = (A0##S[0] != 0) ? s0 : NEGBIG; s1 = (A0##S[1] != 0) ? s1 : NEGBIG;      \
    s2 = (A0##S[2] != 0) ? s2 : NEGBIG; s3 = (A0##S[3] != 0) ? s3 : NEGBIG;      \
    s4 = (A1##S[0] != 0) ? s4 : NEGBIG; s5 = (A1##S[1] != 0) ? s5 : NEGBIG;      \
    s6 = (A1##S[2] != 0) ? s6 : NEGBIG; s7 = (A1##S[3] != 0) ? s7 : NEGBIG;      \
    float p0 = __builtin_exp2f(s0), p1 = __builtin_exp2f(s1);                    \
    float p2 = __builtin_exp2f(s2), p3 = __builtin_exp2f(s3);                    \
    float p4 = __builtin_exp2f(s4), p5 = __builtin_exp2f(s5);                    \
    float p6 = __builtin_exp2f(s6), p7 = __builtin_exp2f(s7);                    \
    bf16x8 af;                                                                   \
    af[0] = (__bf16)p0; af[1] = (__bf16)p1; af[2] = (__bf16)p2; af[3] = (__bf16)p3; \
    af[4] = (__bf16)p4; af[5] = (__bf16)p5; af[6] = (__bf16)p6; af[7] = (__bf16)p7; \
    acc0 = __builtin_amdgcn_mfma_f32_16x16x32_bf16(af, __builtin_bit_cast(bf16x8, B0##S), acc0, 0, 0, 0); \
    acc1 = __builtin_amdgcn_mfma_f32_16x16x32_bf16(af, __builtin_bit_cast(bf16x8, B1##S), acc1, 0, 0, 0); \
    acc2 = __builtin_amdgcn_mfma_f32_16x16x32_bf16(af, __builtin_bit_cast(bf16x8, B2##S), acc2, 0, 0, 0); \
    acc3 = __builtin_amdgcn_mfma_f32_16x16x32_bf16(af, __builtin_bit_cast(bf16x8, B3##S), acc3, 0, 0, 0); \
    acc4 = __builtin_amdgcn_mfma_f32_16x16x32_bf16(af, bOnes, acc4, 0, 0, 0);    \
}

__global__ __launch_bounds__(512, 4) void k3_flash(const int* __restrict__ adj,
                                                   const unsigned short* __restrict__ hB,
                                                   const float* __restrict__ esrc,
                                                   const float* __restrict__ edst,
                                                   float* __restrict__ out) {
    __shared__ float lacc[8][16][64];
    __shared__ float lls[8][16];

    const int lane = threadIdx.x & 63;
    const int w  = threadIdx.x >> 6;  // 0..7
    const int q  = w >> 1;            // j-split 0..3
    const int hd = w & 1;             // head within pair
    const int hb = blockIdx.x & 1;    // head pair
    const int ib = blockIdx.x >> 1;   // 0..255
    const int hh = hb * 2 + hd;
    const int i0 = ib * 16;
    const int row = lane & 15;
    const int kg  = lane >> 4;

    const float es = esrc[hh * NN + i0 + row];
    const int* aRow = adj + (i0 + row) * NN + q * 1024 + kg * 8;
    const float* eD = edst + hh * NN + q * 1024 + kg * 8;
    const unsigned short* hBp = hB + ((hh * 128 + q * 32) * 256 + lane) * 8;

    // ones B-fragment: column 0 only
    u16x8 ou;
    const unsigned short ov = (row == 0) ? (unsigned short)0x3F80 : (unsigned short)0;
#pragma unroll
    for (int e = 0; e < 8; ++e) ou[e] = ov;
    const bf16x8 bOnes = __builtin_bit_cast(bf16x8, ou);

    f32x4 acc0 = (f32x4)0.f, acc1 = (f32x4)0.f, acc2 = (f32x4)0.f,
          acc3 = (f32x4)0.f, acc4 = (f32x4)0.f;

    i32x4 A0a, A1a, A0b, A1b;
    f32x4 E0a, E1a, E0b, E1b;
    u16x8 B0a, B1a, B2a, B3a, B0b, B1b, B2b, B3b;

    K3_LOAD(a, 0)
    for (int t = 0; t < 32; t += 2) {
        K3_LOAD(b, t + 1)
        K3_COMPUTE(a)
        if (t + 2 < 32) { K3_LOAD(a, t + 2) }
        K3_COMPUTE(b)
    }

    // stash wave partials in LDS
#pragma unroll
    for (int n = 0; n < 4; ++n) {
        f32x4 an = (n == 0) ? acc0 : (n == 1) ? acc1 : (n == 2) ? acc2 : acc3;
#pragma unroll
        for (int r = 0; r < 4; ++r)
            lacc[w][kg * 4 + r][n * 16 + row] = an[r];
    }
    if (row == 0) {
#pragma unroll
        for (int r = 0; r < 4; ++r)
            lls[w][kg * 4 + r] = acc4[r];
    }
    __syncthreads();

    // merge 4 j-splits, normalize, write final out
    const int idx = threadIdx.x * 4;   // 0..2047
    const int r2  = idx >> 7;          // row 0..15
    const int c2  = idx & 127;         // col-pair 0..127
    const int hd2 = c2 >> 6;
    const int c   = c2 & 63;
    f32x4 v = (f32x4)0.f;
    float l = 0.f;
#pragma unroll
    for (int q2 = 0; q2 < 4; ++q2) {
        v += *(const f32x4*)&lacc[q2 * 2 + hd2][r2][c];
        l += lls[q2 * 2 + hd2][r2];
    }
    const float inv = 1.f / l;
    f32x4 o;
    o[0] = v[0] * inv; o[1] = v[1] * inv; o[2] = v[2] * inv; o[3] = v[3] * inv;
    *(f32x4*)(out + (i0 + r2) * 256 + hb * 128 + c2) = o;
}

extern "C" void kernel_launch(void* const* d_in, const int* in_sizes, int n_in,
                              void* d_out, int out_size, void* d_ws, size_t ws_size,
                              hipStream_t stream) {
    const float* X    = (const float*)d_in[0];
    const int*   adj  = (const int*)d_in[1];
    const float* W    = (const float*)d_in[2];
    const float* bias = (const float*)d_in[3];
    const float* a    = (const float*)d_in[4];
    float* out = (float*)d_out;

    char* ws = (char*)d_ws;
    float*          h    = (float*)(ws);                                  // 4 MB
    unsigned short* hB   = (unsigned short*)(ws + (4 << 20));             // 2 MB
    float*          esrc = (float*)(ws + (6 << 20));                      // 16 KB
    float*          edst = (float*)(ws + (6 << 20) + (64 << 10));         // 16 KB

    k1_gemm<<<256, 256, 0, stream>>>(X, W, bias, h);
    k2_edges<<<1024, 256, 0, stream>>>(h, a, esrc, edst);
    k2_swizzle<<<512, 256, 0, stream>>>(h, hB);
    k3_flash<<<512, 512, 0, stream>>>(adj, hB, esrc, edst, out);
}